// Round 5
// baseline (6076.704 us; speedup 1.0000x reference)
//
#include <hip/hip_runtime.h>

typedef __attribute__((ext_vector_type(8))) short short8;
typedef __attribute__((ext_vector_type(4))) float f32x4;
typedef __attribute__((ext_vector_type(4))) unsigned int u32x4;

#define MFMA(a,b,c) __builtin_amdgcn_mfma_f32_16x16x32_bf16((a),(b),(c),0,0,0)

#define B_  16
#define S_  512
#define DM_ 768
#define H_  640
#define G4_ 2560
#define DA_ 1280
#define NH_ 10
#define HD_ 128
#define U_   40      // hidden units per WG
#define NWG_ 16      // WGs per direction
#define SLABB_ 1280  // bytes per producer h-slab (16 b x 40 u x bf16)

static __device__ __forceinline__ unsigned short f2bf(float v) {
  unsigned u = __builtin_bit_cast(unsigned, v);
  u = (u + 0x7fffu + ((u >> 16) & 1u)) >> 16;
  return (unsigned short)u;
}
static __device__ __forceinline__ float bf2f(unsigned short u) {
  return __builtin_bit_cast(float, (unsigned)u << 16);
}
static __device__ __forceinline__ float sigm(float x) { return 1.0f / (1.0f + __expf(-x)); }
static __device__ __forceinline__ float tanh_c(float x) {
  x = fminf(fmaxf(x, -15.0f), 15.0f);
  float e = __expf(2.0f * x);
  return (e - 1.0f) / (e + 1.0f);
}

// ---- LLC-coherent (L1/L2-bypassing) access helpers --------------------------
static __device__ __forceinline__ u32x4 load_coh16(const void* p) {
  u32x4 r;
  asm volatile("global_load_dwordx4 %0, %1, off sc0 sc1"
               : "=v"(r) : "v"(p) : "memory");
  return r;
}
static __device__ __forceinline__ void store_coh16(void* p, u32x4 v) {
  asm volatile("global_store_dwordx4 %0, %1, off sc0 sc1"
               :: "v"(p), "v"(v) : "memory");
}
static __device__ __forceinline__ void store_coh_u32(void* p, unsigned v) {
  asm volatile("global_store_dword %0, %1, off sc0 sc1"
               :: "v"(p), "v"(v) : "memory");
}
// fused load+wait: returned register is architecturally valid
static __device__ __forceinline__ unsigned poll_u32(const void* p) {
  unsigned r;
  asm volatile("global_load_dword %0, %1, off sc0 sc1\n\ts_waitcnt vmcnt(0)"
               : "=v"(r) : "v"(p) : "memory");
  return r;
}
#define WAIT_VM0() asm volatile("s_waitcnt vmcnt(0)" ::: "memory")

// ---------------------------------------------------------------- cast f32->bf16
__global__ __launch_bounds__(256)
void cast_f32_bf16(const float* __restrict__ src, unsigned short* __restrict__ dst, int n4) {
  int i = blockIdx.x * 256 + threadIdx.x;
  if (i >= n4) return;
  float4 v = reinterpret_cast<const float4*>(src)[i];
  ushort4 o;
  o.x = f2bf(v.x); o.y = f2bf(v.y); o.z = f2bf(v.z); o.w = f2bf(v.w);
  reinterpret_cast<ushort4*>(dst)[i] = o;
}

// ---------------------------------------------------------------- GEMM  C = A @ W^T + bias
// OUT_MODE 1: bf16 C[M][N]; 2: bf16 per-head-transposed V;
// 3: f32 xp-scatter [slice][t][gate][u(40)][b(16)]; 4: bf16 same layout.
__device__ __forceinline__ void gload_lds16(void* lds, const void* g) {
  __builtin_amdgcn_global_load_lds(
      (const __attribute__((address_space(1))) unsigned int*)g,
      (__attribute__((address_space(3))) unsigned int*)lds, 16, 0, 0);
}

template<int OUT_MODE>
__global__ __launch_bounds__(256)
void gemm_abt(const unsigned short* __restrict__ A, const unsigned short* __restrict__ W,
              const float* __restrict__ bias, void* __restrict__ Cout,
              int M, int N, int K) {
  __shared__ unsigned short lA[128 * 32];
  __shared__ unsigned short lB[128 * 32];
  const int tid = threadIdx.x;
  const int lane = tid & 63, wid = tid >> 6;
  const int nbn = N >> 7;
  const int mi = blockIdx.x / nbn, ni = blockIdx.x % nbn;
  const int l15 = lane & 15, lq = lane >> 4;

  f32x4 acc[4][4] = {};

  for (int k0 = 0; k0 < K; k0 += 32) {
#pragma unroll
    for (int part = 0; part < 2; ++part) {
      int linear = part * 256 + tid;
      int r = linear >> 2, cc = linear & 3;
      const unsigned short* ga = A + (size_t)(mi * 128 + r) * K + k0 + cc * 8;
      const unsigned short* gb = W + (size_t)(ni * 128 + r) * K + k0 + cc * 8;
      gload_lds16(&lA[(part * 256 + wid * 64) * 8], ga);
      gload_lds16(&lB[(part * 256 + wid * 64) * 8], gb);
    }
    __syncthreads();
    const int wm = (wid >> 1) * 64, wn = (wid & 1) * 64;
    short8 af[4], bfr[4];
#pragma unroll
    for (int m = 0; m < 4; ++m)
      af[m] = *(const short8*)&lA[(wm + m * 16 + l15) * 32 + lq * 8];
#pragma unroll
    for (int n = 0; n < 4; ++n)
      bfr[n] = *(const short8*)&lB[(wn + n * 16 + l15) * 32 + lq * 8];
#pragma unroll
    for (int m = 0; m < 4; ++m)
#pragma unroll
      for (int n = 0; n < 4; ++n)
        acc[m][n] = MFMA(af[m], bfr[n], acc[m][n]);
    __syncthreads();
  }

  const int wm = (wid >> 1) * 64, wn = (wid & 1) * 64;
#pragma unroll
  for (int n = 0; n < 4; ++n) {
    int col = ni * 128 + wn + n * 16 + l15;
    float bv = bias[col];
#pragma unroll
    for (int m = 0; m < 4; ++m) {
#pragma unroll
      for (int r = 0; r < 4; ++r) {
        int row = mi * 128 + wm + m * 16 + lq * 4 + r;
        float v = acc[m][n][r] + bv;
        if (OUT_MODE == 1) {
          ((unsigned short*)Cout)[(size_t)row * N + col] = f2bf(v);
        } else if (OUT_MODE == 2) {
          int bb = row >> 9, s = row & 511, hh = col >> 7, d = col & 127;
          ((unsigned short*)Cout)[(((size_t)(bb * NH_ + hh) * HD_ + d) << 9) + s] = f2bf(v);
        } else {
          int gate = col / 640, un = col % 640;
          int sl = un / U_, uu = un % U_;
          int bb = row >> 9, tt = row & 511;
          size_t idx = ((((size_t)sl * S_ + tt) * 4 + gate) * U_ + uu) * 16 + bb;
          if (OUT_MODE == 3) ((float*)Cout)[idx] = v;
          else               ((unsigned short*)Cout)[idx] = f2bf(v);
        }
      }
    }
  }
}

// ---------------------------------------------------------------- persistent BiLSTM layer
// grid = 32 WGs (16/dir) x 640 threads (10 waves). Each WG owns 40 hidden units.
// Whh B-fragments live in REGISTERS (80 VGPR/lane); rows gate-interleaved
// (row = unit*4+gate) so the 4 gates of a (unit,batch) sit in 4 adjacent lanes
// -> gate math via 3 quad shfl_xor, no LDS round trip. Exchange: staged LDS ->
// wave8 publishes 1.25KB slab (coherent dwordx4) + drain + 1 flag; waves 0..7
// poll 2 flags each (1 fused load+wait per retry) then bulk-read + ds_write_b128
// scatter into hbuf. 2 barriers/step.
template<bool XPF32>
__global__ __launch_bounds__(640)
void bilstm_layer(const void* __restrict__ xp_,            // [16][S][4][40][16] per dir
                  const unsigned short* __restrict__ whh_g,// [2][2560][640] bf16
                  const int* __restrict__ lengths,
                  char* __restrict__ h_ex2,                // [2][2][16][SLABB_]
                  int* __restrict__ flags,                 // [2*16][32] ints
                  unsigned short* __restrict__ out_bf)     // [B*S][1280] bf16
{
  __shared__ unsigned short hbuf[16 * 648];
  __shared__ unsigned short staged[16 * U_];
  __shared__ int len_s[16];

  const int tid = threadIdx.x;
  const int lane = tid & 63, w = tid >> 6;
  const int wg = blockIdx.x;
  const int dir = wg >> 4, slice = wg & 15;
  const int J0 = slice * U_;
  const int l15 = lane & 15, lq = lane >> 4;
  const int uloc = 4 * w + (l15 >> 2);   // unit within WG, 0..39
  const int gate = l15 & 3;

  // ---- preload Whh B-fragments into registers (row = gate*640 + J0 + uloc)
  short8 bfr[20];
  {
    const unsigned short* wrow =
        whh_g + ((size_t)dir * G4_ + gate * H_ + J0 + uloc) * H_ + lq * 8;
#pragma unroll
    for (int kk = 0; kk < 20; ++kk) bfr[kk] = *(const short8*)(wrow + kk * 32);
  }
  if (tid < 16) len_s[tid] = lengths[tid];
  for (int c = tid; c < 16 * 648; c += 640) hbuf[c] = 0;
  __syncthreads();

  float cst[4] = {0.f, 0.f, 0.f, 0.f};
  float hst[4] = {0.f, 0.f, 0.f, 0.f};

  const char* xps = (const char*)xp_ +
      ((size_t)dir * NWG_ + slice) * S_ * (4 * U_ * 16) * (XPF32 ? 4 : 2);
  // per-lane xp offset within a step block: ((gate)*40 + uloc)*16 + lq*4
  const int xoff_e = (gate * U_ + uloc) * 16 + lq * 4;

  float4  xvf; ushort4 xvh;
  {
    int t0 = dir ? (S_ - 1) : 0;
    if (XPF32) xvf = *(const float4*)(xps + ((size_t)t0 * (4*U_*16) + xoff_e) * 4);
    else       xvh = *(const ushort4*)(xps + ((size_t)t0 * (4*U_*16) + xoff_e) * 2);
  }

  for (int s = 0; s < S_; ++s) {
    const int t = dir ? (S_ - 1 - s) : s;

    // ---- MFMA: pre[b][gaterow] ; A from hbuf, B from registers
    f32x4 a0 = {0.f,0.f,0.f,0.f}, a1 = {0.f,0.f,0.f,0.f};
#pragma unroll
    for (int kk = 0; kk < 20; kk += 2) {
      short8 av0 = *(const short8*)&hbuf[l15 * 648 + kk * 32 + lq * 8];
      a0 = MFMA(av0, bfr[kk], a0);
      short8 av1 = *(const short8*)&hbuf[l15 * 648 + (kk + 1) * 32 + lq * 8];
      a1 = MFMA(av1, bfr[kk + 1], a1);
    }

    // ---- gates in-register (quad shfl); lane owns (gaterow=l15, b=lq*4+r)
    float yv[4];
#pragma unroll
    for (int r = 0; r < 4; ++r) {
      float xq = XPF32 ? ((const float*)&xvf)[r] : bf2f(((const unsigned short*)&xvh)[r]);
      float pre = a0[r] + a1[r] + xq;
      float x1 = __shfl_xor(pre, 1);
      float x2 = __shfl_xor(pre, 2);
      float x3 = __shfl_xor(pre, 3);
      float ip = gate == 0 ? pre : gate == 1 ? x1 : gate == 2 ? x2 : x3;
      float fp = gate == 0 ? x1 : gate == 1 ? pre : gate == 2 ? x3 : x2;
      float gp = gate == 0 ? x2 : gate == 1 ? x3 : gate == 2 ? pre : x1;
      float op = gate == 0 ? x3 : gate == 1 ? x2 : gate == 2 ? x1 : pre;
      float i_ = sigm(ip), f_ = sigm(fp);
      float g_ = tanh_c(gp), o_ = sigm(op);
      float c2 = f_ * cst[r] + i_ * g_;
      float h2 = o_ * tanh_c(c2);
      int b = lq * 4 + r;
      bool valid = t < len_s[b];
      cst[r] = valid ? c2 : cst[r];
      hst[r] = valid ? h2 : hst[r];
      yv[r] = valid ? hst[r] : 0.f;
      if (gate == 0) staged[b * U_ + uloc] = f2bf(hst[r]);
    }
    __syncthreads();   // [C] staged complete; hbuf reads done

    if (s + 1 < S_) {
      const int tgt = s + 1;
      char* par_base = h_ex2 + (size_t)((dir * 2 + ((s + 1) & 1)) * NWG_) * SLABB_;
      if (w == 8) {
        // ---- publish: 80 16B chunks (lane + [lane<16: 64+lane])
        u32x4 d0 = *(const u32x4*)&staged[lane * 8];
        u32x4 d1 = *(const u32x4*)&staged[(64 + (lane & 15)) * 8];
        char* myslab = par_base + (size_t)slice * SLABB_;
        store_coh16(myslab + lane * 16, d0);
        if (lane < 16) store_coh16(myslab + (64 + lane) * 16, d1);
        WAIT_VM0();
        if (lane == 0)
          store_coh_u32(flags + (size_t)(dir * NWG_ + slice) * 32, (unsigned)tgt);
      } else if (w < 8) {
        // ---- poll 2 producers (1 fused load+wait per retry), then bulk read
        const int pA = 2 * w, pB = 2 * w + 1;
        const int* fp = flags + (size_t)(dir * NWG_ + (lane < 32 ? pA : pB)) * 32;
        for (;;) {
          unsigned v = poll_u32(fp);
          if (__all((int)v >= tgt)) break;
        }
        const char* sA = par_base + (size_t)pA * SLABB_;
        const char* sB = par_base + (size_t)pB * SLABB_;
        u32x4 qA0 = load_coh16(sA + lane * 16);
        u32x4 qA1 = load_coh16(sA + (64 + (lane & 15)) * 16);
        u32x4 qB0 = load_coh16(sB + lane * 16);
        u32x4 qB1 = load_coh16(sB + (64 + (lane & 15)) * 16);
        WAIT_VM0();
        __builtin_amdgcn_sched_barrier(0);
        {
          int c = lane, b = c / 5, m = c - 5 * b;
          *(u32x4*)&hbuf[b * 648 + pA * U_ + m * 8] = qA0;
          *(u32x4*)&hbuf[b * 648 + pB * U_ + m * 8] = qB0;
        }
        if (lane < 16) {
          int c = 64 + lane, b = c / 5, m = c - 5 * b;
          *(u32x4*)&hbuf[b * 648 + pA * U_ + m * 8] = qA1;
          *(u32x4*)&hbuf[b * 648 + pB * U_ + m * 8] = qB1;
        }
      }
    }

    // ---- off-critical-path: output stores + next xp prefetch
    if (gate == 0) {
#pragma unroll
      for (int r = 0; r < 4; ++r) {
        int b = lq * 4 + r;
        out_bf[((size_t)(b * S_ + t)) * DA_ + dir * H_ + J0 + uloc] = f2bf(yv[r]);
      }
    }
    {
      int tn = dir ? (S_ - 2 - s) : (s + 1);
      tn = tn < 0 ? 0 : (tn > S_ - 1 ? S_ - 1 : tn);
      if (XPF32) xvf = *(const float4*)(xps + ((size_t)tn * (4*U_*16) + xoff_e) * 4);
      else       xvh = *(const ushort4*)(xps + ((size_t)tn * (4*U_*16) + xoff_e) * 2);
    }
    __syncthreads();   // [A] hbuf ready for next step
  }
}

// ---------------------------------------------------------------- fused attention + residual
__global__ __launch_bounds__(256)
void attn_fused(const unsigned short* __restrict__ q, const unsigned short* __restrict__ k,
                const unsigned short* __restrict__ vT, const float* __restrict__ mask,
                const unsigned short* __restrict__ h1, float* __restrict__ out)
{
  __shared__ unsigned short p_lds[64 * 512];
  const int tid = threadIdx.x, lane = tid & 63, wid = tid >> 6;
  const int bx = blockIdx.x;
  const int b = bx / 80, rem = bx % 80, h = rem / 8, qt = rem % 8;
  const int l15 = lane & 15, lq = lane >> 4;
  const int qrow0 = qt * 64 + wid * 16;

  short8 qf[4];
  {
    const unsigned short* qb = q + ((size_t)(b * S_ + qrow0 + l15)) * DA_ + h * HD_ + lq * 8;
#pragma unroll
    for (int ks = 0; ks < 4; ++ks) qf[ks] = *(const short8*)(qb + ks * 32);
  }
  f32x4 sc[32];
#pragma unroll
  for (int nt = 0; nt < 32; ++nt) {
    f32x4 a = {0.f, 0.f, 0.f, 0.f};
    const unsigned short* kb = k + ((size_t)(b * S_ + nt * 16 + l15)) * DA_ + h * HD_ + lq * 8;
#pragma unroll
    for (int ks = 0; ks < 4; ++ks) {
      short8 bf = *(const short8*)(kb + ks * 32);
      a = MFMA(qf[ks], bf, a);
    }
    sc[nt] = a;
  }
  const float scl = 0.08838834764831845f;  // 1/sqrt(128)
  float mx[4] = {-1e30f, -1e30f, -1e30f, -1e30f};
#pragma unroll
  for (int nt = 0; nt < 32; ++nt) {
    float mv = mask[b * S_ + nt * 16 + l15];
#pragma unroll
    for (int r = 0; r < 4; ++r) {
      float v = sc[nt][r] * scl + mv;
      sc[nt][r] = v;
      mx[r] = fmaxf(mx[r], v);
    }
  }
#pragma unroll
  for (int r = 0; r < 4; ++r) {
    mx[r] = fmaxf(mx[r], __shfl_xor(mx[r], 1));
    mx[r] = fmaxf(mx[r], __shfl_xor(mx[r], 2));
    mx[r] = fmaxf(mx[r], __shfl_xor(mx[r], 4));
    mx[r] = fmaxf(mx[r], __shfl_xor(mx[r], 8));
  }
  float sm[4] = {0.f, 0.f, 0.f, 0.f};
#pragma unroll
  for (int nt = 0; nt < 32; ++nt)
#pragma unroll
    for (int r = 0; r < 4; ++r) {
      float p = __expf(sc[nt][r] - mx[r]);
      sc[nt][r] = p; sm[r] += p;
    }
#pragma unroll
  for (int r = 0; r < 4; ++r) {
    sm[r] += __shfl_xor(sm[r], 1);
    sm[r] += __shfl_xor(sm[r], 2);
    sm[r] += __shfl_xor(sm[r], 4);
    sm[r] += __shfl_xor(sm[r], 8);
    sm[r] = 1.0f / sm[r];
  }
#pragma unroll
  for (int nt = 0; nt < 32; ++nt)
#pragma unroll
    for (int r = 0; r < 4; ++r) {
      int row = wid * 16 + lq * 4 + r;
      int byte = row * 1024 + (nt * 16 + l15) * 2;
      byte ^= (row & 7) << 4;
      *(unsigned short*)((char*)p_lds + byte) = f2bf(sc[nt][r] * sm[r]);
    }
  __syncthreads();

  f32x4 oa[8] = {};
#pragma unroll
  for (int kk = 0; kk < 16; ++kk) {
    int row = wid * 16 + l15;
    int byte = row * 1024 + (kk * 32 + lq * 8) * 2;
    byte ^= (row & 7) << 4;
    short8 pa = *(const short8*)((char*)p_lds + byte);
    const unsigned short* vb = vT + ((size_t)(b * NH_ + h) * HD_ + l15) * S_ + kk * 32 + lq * 8;
#pragma unroll
    for (int n = 0; n < 8; ++n) {
      short8 bv = *(const short8*)(vb + n * 16 * S_);
      oa[n] = MFMA(pa, bv, oa[n]);
    }
  }
#pragma unroll
  for (int n = 0; n < 8; ++n)
#pragma unroll
    for (int r = 0; r < 4; ++r) {
      int row = qrow0 + lq * 4 + r;
      int col = h * HD_ + n * 16 + l15;
      size_t idx = ((size_t)(b * S_ + row)) * DA_ + col;
      out[idx] = bf2f(h1[idx]) + oa[n][r];
    }
}

// ---------------------------------------------------------------- host
extern "C" void kernel_launch(void* const* d_in, const int* in_sizes, int n_in,
                              void* d_out, int out_size, void* d_ws, size_t ws_size,
                              hipStream_t stream) {
  const float* x    = (const float*)d_in[0];
  const float* mask = (const float*)d_in[1];
  const int*   lens = (const int*)d_in[2];
  const float* Wih0 = (const float*)d_in[3];
  const float* Whh0 = (const float*)d_in[4];
  const float* b0   = (const float*)d_in[5];
  const float* Wih1 = (const float*)d_in[6];
  const float* Whh1 = (const float*)d_in[7];
  const float* b1   = (const float*)d_in[8];
  const float* Wq   = (const float*)d_in[9];
  const float* bq   = (const float*)d_in[10];
  const float* Wk   = (const float*)d_in[11];
  const float* bk   = (const float*)d_in[12];
  const float* Wv   = (const float*)d_in[13];
  const float* bv   = (const float*)d_in[14];

  const size_t SZ_wb_ih1 = (size_t)2 * G4_ * DA_ * 2;
  const size_t SZ_wb_hh  = (size_t)2 * G4_ * H_ * 2;
  const size_t SZ_wb_qkv = (size_t)DA_ * DA_ * 2;
  const size_t SZ_tok_bf = (size_t)B_ * S_ * DA_ * 2;
  const size_t SZ_h_ex2  = (size_t)2 * 2 * NWG_ * SLABB_;  // 81,920
  const size_t SZ_flags  = (size_t)2 * NWG_ * 32 * 4;      //  4,096
  const size_t SZ_xbf    = (size_t)B_ * S_ * DM_ * 2;
  const size_t SZ_wb_ih0 = (size_t)2 * G4_ * DM_ * 2;
  const size_t SZ_regA   = SZ_xbf + SZ_wb_ih0 + SZ_wb_hh;
  const size_t SZ_xp_f32 = (size_t)2 * B_ * S_ * G4_ * 4;
  const size_t SZ_xp_bf  = SZ_xp_f32 / 2;

  const size_t persist = SZ_wb_ih1 + SZ_wb_hh + 3 * SZ_wb_qkv + 2 * SZ_tok_bf
                       + SZ_h_ex2 + SZ_flags;
  const size_t need_A = persist + SZ_regA + SZ_xp_f32;
  const bool xpf32 = (ws_size >= need_A + 4096);

  char* ws = (char*)d_ws;
  size_t off = 0;
  auto alloc = [&](size_t bytes) { char* p = ws + off; off += bytes; return p; };

  unsigned short* wb_ih1 = (unsigned short*)alloc(SZ_wb_ih1);
  unsigned short* wb_hh1 = (unsigned short*)alloc(SZ_wb_hh);
  unsigned short* wb_q   = (unsigned short*)alloc(SZ_wb_qkv);
  unsigned short* wb_k   = (unsigned short*)alloc(SZ_wb_qkv);
  unsigned short* wb_v   = (unsigned short*)alloc(SZ_wb_qkv);
  unsigned short* h0bf   = (unsigned short*)alloc(SZ_tok_bf);
  unsigned short* h1bf   = (unsigned short*)alloc(SZ_tok_bf);
  char*           h_ex2  = alloc(SZ_h_ex2);
  int*            flags  = (int*)alloc(SZ_flags);

  char* regA = alloc(SZ_regA);
  unsigned short* xbf    = (unsigned short*)regA;
  unsigned short* wb_ih0 = (unsigned short*)(regA + SZ_xbf);
  unsigned short* wb_hh0 = (unsigned short*)(regA + SZ_xbf + SZ_wb_ih0);
  unsigned short* qbf    = (unsigned short*)regA;

  char* regB = alloc(xpf32 ? SZ_xp_f32 : SZ_xp_bf);
  void*           xp     = (void*)regB;
  unsigned short* kbf    = (unsigned short*)regB;
  unsigned short* vtbf   = (unsigned short*)(regB + SZ_tok_bf);

  hipMemsetAsync(h_ex2, 0, SZ_h_ex2 + SZ_flags, stream);

  auto cast = [&](const float* s, unsigned short* d, size_t n) {
    int n4 = (int)(n / 4);
    cast_f32_bf16<<<(n4 + 255) / 256, 256, 0, stream>>>(s, d, n4);
  };
  cast(Wih0, wb_ih0, (size_t)2 * G4_ * DM_);
  cast(Whh0, wb_hh0, (size_t)2 * G4_ * H_);
  cast(Wih1, wb_ih1, (size_t)2 * G4_ * DA_);
  cast(Whh1, wb_hh1, (size_t)2 * G4_ * H_);
  cast(Wq, wb_q, (size_t)DA_ * DA_);
  cast(Wk, wb_k, (size_t)DA_ * DA_);
  cast(Wv, wb_v, (size_t)DA_ * DA_);
  cast(x, xbf, (size_t)B_ * S_ * DM_);

  const int M = B_ * S_;  // 8192
  const size_t xp_dir_elems = (size_t)NWG_ * S_ * 4 * U_ * 16;  // = M*G4_

  // layer-0 input projection -> xp scatter layout
  if (xpf32) {
    gemm_abt<3><<<(M / 128) * (G4_ / 128), 256, 0, stream>>>(
        xbf, wb_ih0, b0, xp, M, G4_, DM_);
    gemm_abt<3><<<(M / 128) * (G4_ / 128), 256, 0, stream>>>(
        xbf, wb_ih0 + (size_t)G4_ * DM_, b0 + G4_,
        (float*)xp + xp_dir_elems, M, G4_, DM_);
    bilstm_layer<true><<<32, 640, 0, stream>>>(xp, wb_hh0, lens, h_ex2, flags, h0bf);
  } else {
    gemm_abt<4><<<(M / 128) * (G4_ / 128), 256, 0, stream>>>(
        xbf, wb_ih0, b0, xp, M, G4_, DM_);
    gemm_abt<4><<<(M / 128) * (G4_ / 128), 256, 0, stream>>>(
        xbf, wb_ih0 + (size_t)G4_ * DM_, b0 + G4_,
        (unsigned short*)xp + xp_dir_elems, M, G4_, DM_);
    bilstm_layer<false><<<32, 640, 0, stream>>>(xp, wb_hh0, lens, h_ex2, flags, h0bf);
  }

  // layer-1 input projection (reuse xp)
  if (xpf32) {
    gemm_abt<3><<<(M / 128) * (G4_ / 128), 256, 0, stream>>>(
        h0bf, wb_ih1, b1, xp, M, G4_, DA_);
    gemm_abt<3><<<(M / 128) * (G4_ / 128), 256, 0, stream>>>(
        h0bf, wb_ih1 + (size_t)G4_ * DA_, b1 + G4_,
        (float*)xp + xp_dir_elems, M, G4_, DA_);
  } else {
    gemm_abt<4><<<(M / 128) * (G4_ / 128), 256, 0, stream>>>(
        h0bf, wb_ih1, b1, xp, M, G4_, DA_);
    gemm_abt<4><<<(M / 128) * (G4_ / 128), 256, 0, stream>>>(
        h0bf, wb_ih1 + (size_t)G4_ * DA_, b1 + G4_,
        (unsigned short*)xp + xp_dir_elems, M, G4_, DA_);
  }
  // reset exchange state for layer 1
  hipMemsetAsync(h_ex2, 0, SZ_h_ex2 + SZ_flags, stream);
  if (xpf32)
    bilstm_layer<true><<<32, 640, 0, stream>>>(xp, wb_hh1, lens, h_ex2, flags, h1bf);
  else
    bilstm_layer<false><<<32, 640, 0, stream>>>(xp, wb_hh1, lens, h_ex2, flags, h1bf);

  // QKV (qbf overlays dead xbf/wb_ih0; kbf/vtbf overlay dead xp)
  gemm_abt<1><<<(M / 128) * (DA_ / 128), 256, 0, stream>>>(
      h1bf, wb_q, bq, qbf, M, DA_, DA_);
  gemm_abt<1><<<(M / 128) * (DA_ / 128), 256, 0, stream>>>(
      h1bf, wb_k, bk, kbf, M, DA_, DA_);
  gemm_abt<2><<<(M / 128) * (DA_ / 128), 256, 0, stream>>>(
      h1bf, wb_v, bv, vtbf, M, DA_, DA_);
  attn_fused<<<B_ * NH_ * 8, 256, 0, stream>>>(qbf, kbf, vtbf, mask, h1bf,
                                               (float*)d_out);
}